// Round 2
// baseline (2333.297 us; speedup 1.0000x reference)
//
#include <hip/hip_runtime.h>
#include <hip/hip_bf16.h>

#define NPOS 4096
#define NB   64
#define HD   64
#define XDIM 4

__device__ __forceinline__ float sigm(float x) { return 1.0f / (1.0f + __expf(-x)); }
__device__ __forceinline__ float tanh_f(float x) { return 1.0f - 2.0f / (1.0f + __expf(2.0f * x)); }

// Accumulate one input-row of a weight matrix into a 64-wide register array.
// Weight address is wave-uniform -> scalar s_load batches; FMA takes SGPR operand.
#define ACC_ROW(Arr, Wp, rowoff, v) do {                       \
    const float* __restrict__ _w = (Wp) + (rowoff);            \
    _Pragma("unroll")                                          \
    for (int _j = 0; _j < 64; ++_j) (Arr)[_j] += (v) * _w[_j]; \
} while (0)

#define SET_BIAS(Arr, Bp) do {                                 \
    const float* __restrict__ _b = (Bp);                       \
    _Pragma("unroll")                                          \
    for (int _j = 0; _j < 64; ++_j) (Arr)[_j] = _b[_j];        \
} while (0)

#define ADD_BIAS(Arr, Bp) do {                                 \
    const float* __restrict__ _b = (Bp);                       \
    _Pragma("unroll")                                          \
    for (int _j = 0; _j < 64; ++_j) (Arr)[_j] += _b[_j];       \
} while (0)

__global__ __launch_bounds__(128, 2) void kgnn_kernel(
    const float* __restrict__ hx,  const float* __restrict__ pcm,
    const float* __restrict__ fcm, const float* __restrict__ ycm,
    const float* __restrict__ hy,
    const float* __restrict__ pcW1, const float* __restrict__ pcb1,
    const float* __restrict__ pcW2, const float* __restrict__ pcb2,
    const float* __restrict__ fcW1, const float* __restrict__ fcb1,
    const float* __restrict__ fcW2, const float* __restrict__ fcb2,
    const float* __restrict__ ycW1, const float* __restrict__ ycb1,
    const float* __restrict__ ycW2, const float* __restrict__ ycb2,
    const float* __restrict__ ndW1, const float* __restrict__ ndb1,
    const float* __restrict__ ndW2, const float* __restrict__ ndb2,
    const float* __restrict__ Wih,  const float* __restrict__ bih,
    const float* __restrict__ Whh,  const float* __restrict__ bhh,
    const float* __restrict__ dW1,  const float* __restrict__ db1,
    const float* __restrict__ dW2,  const float* __restrict__ db2,
    float* __restrict__ out)
{
    const int tid = threadIdx.x;
    const int gid = blockIdx.x * 128 + tid;
    const int b  = gid >> 12;            // / NPOS
    const int n  = gid & (NPOS - 1);
    const int nm = (n == 0) ? 0 : n - 1;
    const int np = (n == NPOS - 1) ? (NPOS - 1) : n + 1;

    // Per-thread scratch row for dynamically-indexed intermediates.
    // Stride 65 floats -> bank (tid*65+i)%32 varies -> 2-way aliasing only (free, m136).
    __shared__ float scr[128][65];
    float* __restrict__ S = scr[tid];

    const int baseH = b * HD * NPOS;
    const int baseX = b * XDIM * NPOS;
    const float* __restrict__ hxb = hx + baseH;
    const float* __restrict__ hyb = hy + baseH;

    float T[64], ACC[64];

    // ================= pc MLP: relu(relu([hx_past|hx|pcm] W1 + b1) W2 + b2) ==========
    SET_BIAS(T, pcb1);
    #pragma unroll 1
    for (int i = 0; i < 64; ++i) { float v = hxb[i*NPOS + nm]; ACC_ROW(T, pcW1, i*64, v); }
    #pragma unroll 1
    for (int i = 0; i < 64; ++i) { float v = hxb[i*NPOS + n];  ACC_ROW(T, pcW1, (64+i)*64, v); }
    #pragma unroll
    for (int k = 0; k < 4; ++k)  { float v = pcm[baseX + k*NPOS + n]; ACC_ROW(T, pcW1, (128+k)*64, v); }
    #pragma unroll
    for (int j = 0; j < 64; ++j) S[j] = fmaxf(T[j], 0.f);
    SET_BIAS(T, pcb2);
    #pragma unroll 1
    for (int i = 0; i < 64; ++i) { float v = S[i]; ACC_ROW(T, pcW2, i*64, v); }
    #pragma unroll
    for (int j = 0; j < 64; ++j) ACC[j] = fmaxf(T[j], 0.f);           // ACC = pe

    // ================= fc MLP =================
    SET_BIAS(T, fcb1);
    #pragma unroll 1
    for (int i = 0; i < 64; ++i) { float v = hxb[i*NPOS + np]; ACC_ROW(T, fcW1, i*64, v); }
    #pragma unroll 1
    for (int i = 0; i < 64; ++i) { float v = hxb[i*NPOS + n];  ACC_ROW(T, fcW1, (64+i)*64, v); }
    #pragma unroll
    for (int k = 0; k < 4; ++k)  { float v = fcm[baseX + k*NPOS + n]; ACC_ROW(T, fcW1, (128+k)*64, v); }
    #pragma unroll
    for (int j = 0; j < 64; ++j) S[j] = fmaxf(T[j], 0.f);
    SET_BIAS(T, fcb2);
    #pragma unroll 1
    for (int i = 0; i < 64; ++i) { float v = S[i]; ACC_ROW(T, fcW2, i*64, v); }
    #pragma unroll
    for (int j = 0; j < 64; ++j) ACC[j] += fmaxf(T[j], 0.f);          // += fe

    // ================= yc MLP =================
    SET_BIAS(T, ycb1);
    #pragma unroll 1
    for (int i = 0; i < 64; ++i) { float v = hyb[i*NPOS + n];  ACC_ROW(T, ycW1, i*64, v); }
    #pragma unroll 1
    for (int i = 0; i < 64; ++i) { float v = hxb[i*NPOS + n];  ACC_ROW(T, ycW1, (64+i)*64, v); }
    #pragma unroll
    for (int k = 0; k < 4; ++k)  { float v = ycm[baseX + k*NPOS + n]; ACC_ROW(T, ycW1, (128+k)*64, v); }
    #pragma unroll
    for (int j = 0; j < 64; ++j) S[j] = fmaxf(T[j], 0.f);
    SET_BIAS(T, ycb2);
    #pragma unroll 1
    for (int i = 0; i < 64; ++i) { float v = S[i]; ACC_ROW(T, ycW2, i*64, v); }
    #pragma unroll
    for (int j = 0; j < 64; ++j) ACC[j] += fmaxf(T[j], 0.f);          // ACC = pe+fe+ye

    // ================= nd MLP -> U =================
    #pragma unroll
    for (int j = 0; j < 64; ++j) S[j] = ACC[j];
    SET_BIAS(T, ndb1);
    #pragma unroll 1
    for (int i = 0; i < 64; ++i) { float v = S[i]; ACC_ROW(T, ndW1, i*64, v); }
    #pragma unroll
    for (int j = 0; j < 64; ++j) S[j] = fmaxf(T[j], 0.f);
    SET_BIAS(T, ndb2);
    #pragma unroll 1
    for (int i = 0; i < 64; ++i) { float v = S[i]; ACC_ROW(T, ndW2, i*64, v); }
    #pragma unroll
    for (int j = 0; j < 64; ++j) S[j] = fmaxf(T[j], 0.f);             // S = U (in LDS)

    // ================= GRU =================
    // hg pass: T = b_hh[128:] + hprev @ W_hh[:,128:192]
    SET_BIAS(T, bhh + 128);
    #pragma unroll 1
    for (int i = 0; i < 64; ++i) { float hp = hxb[i*NPOS + n]; ACC_ROW(T, Whh, i*192 + 128, hp); }
    // r pass: ACC = b_ih[0:]+b_hh[0:] + U@W_ih[:,0:64] + hprev@W_hh[:,0:64]
    SET_BIAS(ACC, bih); ADD_BIAS(ACC, bhh);
    #pragma unroll 1
    for (int i = 0; i < 64; ++i) {
        float u  = S[i];
        float hp = hxb[i*NPOS + n];
        ACC_ROW(ACC, Wih, i*192, u);
        ACC_ROW(ACC, Whh, i*192, hp);
    }
    #pragma unroll
    for (int j = 0; j < 64; ++j) T[j] = sigm(ACC[j]) * T[j];          // T = r * hg
    // ig pass
    SET_BIAS(ACC, bih + 128);
    #pragma unroll 1
    for (int i = 0; i < 64; ++i) { float u = S[i]; ACC_ROW(ACC, Wih, i*192 + 128, u); }
    #pragma unroll
    for (int j = 0; j < 64; ++j) T[j] = tanh_f(ACC[j] + T[j]);        // T = n-gate
    // z pass
    SET_BIAS(ACC, bih + 64); ADD_BIAS(ACC, bhh + 64);
    #pragma unroll 1
    for (int i = 0; i < 64; ++i) {
        float u  = S[i];
        float hp = hxb[i*NPOS + n];
        ACC_ROW(ACC, Wih, i*192 + 64, u);
        ACC_ROW(ACC, Whh, i*192 + 64, hp);
    }
    float* __restrict__ outH = out + NB*XDIM*NPOS + baseH;
    #pragma unroll
    for (int j = 0; j < 64; ++j) {
        float z  = sigm(ACC[j]);
        float hp = hxb[j*NPOS + n];
        float hn = (1.f - z) * T[j] + z * hp;
        S[j] = hn;
        outH[j*NPOS + n] = hn;                                         // hnew out [B,H,N]
    }

    // ================= decoder =================
    SET_BIAS(T, db1);
    #pragma unroll 1
    for (int i = 0; i < 64; ++i) { float v = S[i]; ACC_ROW(T, dW1, i*64, v); }
    #pragma unroll
    for (int j = 0; j < 64; ++j) S[j] = fmaxf(T[j], 0.f);
    float e0 = db2[0], e1 = db2[1], e2 = db2[2], e3 = db2[3];
    #pragma unroll 1
    for (int i = 0; i < 64; ++i) {
        float v = S[i];
        e0 += v * dW2[i*4 + 0];
        e1 += v * dW2[i*4 + 1];
        e2 += v * dW2[i*4 + 2];
        e3 += v * dW2[i*4 + 3];
    }
    out[baseX + 0*NPOS + n] = e0;
    out[baseX + 1*NPOS + n] = e1;
    out[baseX + 2*NPOS + n] = e2;
    out[baseX + 3*NPOS + n] = e3;
}

extern "C" void kernel_launch(void* const* d_in, const int* in_sizes, int n_in,
                              void* d_out, int out_size, void* d_ws, size_t ws_size,
                              hipStream_t stream) {
    const float* hx   = (const float*)d_in[0];
    const float* pcm  = (const float*)d_in[1];
    const float* fcm  = (const float*)d_in[2];
    const float* ycm  = (const float*)d_in[3];
    const float* hy   = (const float*)d_in[4];
    const float* pcW1 = (const float*)d_in[5];
    const float* pcb1 = (const float*)d_in[6];
    const float* pcW2 = (const float*)d_in[7];
    const float* pcb2 = (const float*)d_in[8];
    const float* fcW1 = (const float*)d_in[9];
    const float* fcb1 = (const float*)d_in[10];
    const float* fcW2 = (const float*)d_in[11];
    const float* fcb2 = (const float*)d_in[12];
    const float* ycW1 = (const float*)d_in[13];
    const float* ycb1 = (const float*)d_in[14];
    const float* ycW2 = (const float*)d_in[15];
    const float* ycb2 = (const float*)d_in[16];
    const float* ndW1 = (const float*)d_in[17];
    const float* ndb1 = (const float*)d_in[18];
    const float* ndW2 = (const float*)d_in[19];
    const float* ndb2 = (const float*)d_in[20];
    const float* Wih  = (const float*)d_in[21];
    const float* bih  = (const float*)d_in[22];
    const float* Whh  = (const float*)d_in[23];
    const float* bhh  = (const float*)d_in[24];
    const float* dW1  = (const float*)d_in[25];
    const float* db1  = (const float*)d_in[26];
    const float* dW2  = (const float*)d_in[27];
    const float* db2  = (const float*)d_in[28];

    dim3 grid((NB * NPOS) / 128), block(128);
    kgnn_kernel<<<grid, block, 0, stream>>>(
        hx, pcm, fcm, ycm, hy,
        pcW1, pcb1, pcW2, pcb2,
        fcW1, fcb1, fcW2, fcb2,
        ycW1, ycb1, ycW2, ycb2,
        ndW1, ndb1, ndW2, ndb2,
        Wih, bih, Whh, bhh,
        dW1, db1, dW2, db2,
        (float*)d_out);
}

// Round 3
// 788.498 us; speedup vs baseline: 2.9592x; 2.9592x over previous
//
#include <hip/hip_runtime.h>

#define NPOS 4096
#define NB   64

typedef unsigned int u32;
typedef unsigned short u16;
typedef __bf16 bf8v __attribute__((ext_vector_type(8)));
typedef __bf16 bf4v __attribute__((ext_vector_type(4)));
typedef float  f4   __attribute__((ext_vector_type(4)));

__device__ __forceinline__ float sigm(float x)   { return 1.0f / (1.0f + __expf(-x)); }
__device__ __forceinline__ float tanh_f(float x) { return 1.0f - 2.0f / (1.0f + __expf(2.0f * x)); }

__device__ __forceinline__ f4 MF(bf8v a, bf8v b, f4 c) {
    return __builtin_amdgcn_mfma_f32_16x16x32_bf16(a, b, c, 0, 0, 0);
}

// ---------------- frag index map (1KB frags in d_ws) ----------------
// 0-19   W1pc [kb*4+t]   20-39 W1fc   40-59 W1yc        (kb=0..4, t=0..3)
// 60-67  W2pc [kb*4+t]   68-75 W2fc   76-83 W2yc        (kb=0..1)
// 84-91  ndW1            92-99 ndW2
// 100-123 Wih [kb*12+t]  124-147 Whh                    (t=0..11)
// 148-155 decW1          156-157 decW2 [kb]
// biases (f32 frags): 158 pcb1(4) 162 pcb2 166 fcb1 170 fcb2 174 ycb1 178 ycb2
// 182 ndb1 186 ndb2 190 bRZ(8) 198 bIG(4) 202 bHG(4) 206 db1(4) 210 db2(1)
#define NFRAG 211

__global__ __launch_bounds__(64) void prep_kernel(
    const float* __restrict__ pcW1, const float* __restrict__ pcb1, const float* __restrict__ pcW2, const float* __restrict__ pcb2,
    const float* __restrict__ fcW1, const float* __restrict__ fcb1, const float* __restrict__ fcW2, const float* __restrict__ fcb2,
    const float* __restrict__ ycW1, const float* __restrict__ ycb1, const float* __restrict__ ycW2, const float* __restrict__ ycb2,
    const float* __restrict__ ndW1, const float* __restrict__ ndb1, const float* __restrict__ ndW2, const float* __restrict__ ndb2,
    const float* __restrict__ Wih,  const float* __restrict__ bih,  const float* __restrict__ Whh,  const float* __restrict__ bhh,
    const float* __restrict__ dW1,  const float* __restrict__ db1,  const float* __restrict__ dW2,  const float* __restrict__ db2,
    char* __restrict__ ws)
{
    const int f = blockIdx.x, l = threadIdx.x;
    const int sg = l >> 4, c16 = l & 15;
    char* dst = ws + (size_t)f * 1024 + (size_t)l * 16;

    if (f < 158) {
        const float* W = nullptr; int t = 0, kb = 0, ncol = 64, mlp = -1, kind = 0;
        if (f < 60)       { mlp = f / 20; int r = f % 20; kb = r >> 2; t = r & 3;
                            W = (mlp == 0 ? pcW1 : (mlp == 1 ? fcW1 : ycW1)); kind = 1; }
        else if (f < 84)  { int g = f - 60; int w = g >> 3; int r = g & 7; kb = r >> 2; t = r & 3;
                            W = (w == 0 ? pcW2 : (w == 1 ? fcW2 : ycW2)); }
        else if (f < 92)  { int r = f - 84; kb = r >> 2; t = r & 3; W = ndW1; }
        else if (f < 100) { int r = f - 92; kb = r >> 2; t = r & 3; W = ndW2; }
        else if (f < 124) { int r = f - 100; kb = r / 12; t = r % 12; W = Wih; ncol = 192; }
        else if (f < 148) { int r = f - 124; kb = r / 12; t = r % 12; W = Whh; ncol = 192; }
        else if (f < 156) { int r = f - 148; kb = r >> 2; t = r & 3; W = dW1; }
        else              { kb = f - 156; t = 0; W = dW2; kind = 2; }
        const int row = 16 * t + c16;
        bf8v v;
        #pragma unroll
        for (int j = 0; j < 8; ++j) {
            int k = kb * 32 + sg * 8 + j;
            float x;
            if (kind == 1 && kb == 4) {            // W1 message block: mlp owns cols mlp*4..+3
                int kk = k - 128 - mlp * 4;
                x = (kk >= 0 && kk < 4) ? W[(128 + kk) * 64 + row] : 0.f;
            } else if (kind == 2) {                // decW2 [64][4], rows 4..15 zero
                x = (row < 4) ? W[k * 4 + row] : 0.f;
            } else {
                x = W[k * ncol + row];
            }
            v[j] = (__bf16)x;
        }
        *(bf8v*)dst = v;
    } else {
        const int g = f - 158;
        f4 o;
        #pragma unroll
        for (int r = 0; r < 4; ++r) {
            float x = 0.f; int t;
            if (g < 32) {
                t = g & 3; int fi = 16 * t + 4 * sg + r;
                switch (g >> 2) {
                    case 0: x = pcb1[fi]; break; case 1: x = pcb2[fi]; break;
                    case 2: x = fcb1[fi]; break; case 3: x = fcb2[fi]; break;
                    case 4: x = ycb1[fi]; break; case 5: x = ycb2[fi]; break;
                    case 6: x = ndb1[fi]; break; default: x = ndb2[fi]; break;
                }
            } else if (g < 40) { t = g - 32; int fi = 16 * t + 4 * sg + r; x = bih[fi] + bhh[fi]; }
            else if (g < 44)   { t = g - 40; x = bih[128 + 16 * t + 4 * sg + r]; }
            else if (g < 48)   { t = g - 44; x = bhh[128 + 16 * t + 4 * sg + r]; }
            else if (g < 52)   { t = g - 48; x = db1[16 * t + 4 * sg + r]; }
            else               { x = (sg == 0) ? db2[r] : 0.f; }
            o[r] = x;
        }
        *(f4*)dst = o;
    }
}

// ---------------- LDS layout (bytes) ----------------
// hxT: rows 0..129 (pos n0-1 .. n0+128), 64 bf16/row (128B), swizzled
#define HXT 0
#define HYT 16640
#define MST 33024
#define ACT 49408
#define LDSZ 65792

__global__ __launch_bounds__(256) void kgnn_main(
    const float* __restrict__ hx,  const float* __restrict__ pcm,
    const float* __restrict__ fcm, const float* __restrict__ ycm,
    const float* __restrict__ hy,
    const char*  __restrict__ ws,  float* __restrict__ out)
{
    __shared__ __align__(16) char LD[LDSZ];
    const int tid  = threadIdx.x;
    const int b    = blockIdx.x >> 5;
    const int tile = blockIdx.x & 31;
    const int n0   = tile * 128;
    const int baseH = b * 64 * NPOS;
    const int baseX = b * 4 * NPOS;

    // ---------------- staging: transpose f32 global -> bf16 position-major LDS ----------------
    #pragma unroll
    for (int it = 0; it < 8; ++it) {
        const int idx = it * 256 + tid;
        const int pp = idx & 127, fg = idx >> 7;          // fg 0..15
        const int gn = n0 + pp;
        // hx (tile rows 1..128)
        {
            bf4v h;
            #pragma unroll
            for (int j = 0; j < 4; ++j) h[j] = (__bf16)hx[baseH + (4 * fg + j) * NPOS + gn];
            const int row = pp + 1;
            *(bf4v*)(LD + HXT + row * 128 + ((8 * fg) ^ ((row & 7) << 4))) = h;
        }
        // hy (rows 0..127)
        {
            bf4v h;
            #pragma unroll
            for (int j = 0; j < 4; ++j) h[j] = (__bf16)hy[baseH + (4 * fg + j) * NPOS + gn];
            *(bf4v*)(LD + HYT + pp * 128 + ((8 * fg) ^ ((pp & 7) << 4))) = h;
        }
        // messages: cols 0-3 pcm, 4-7 fcm, 8-11 ycm, 12-63 zero
        {
            bf4v m;
            #pragma unroll
            for (int j = 0; j < 4; ++j) {
                const int col = 4 * fg + j;
                float x = 0.f;
                if      (col < 4)  x = pcm[baseX + col * NPOS + gn];
                else if (col < 8)  x = fcm[baseX + (col - 4) * NPOS + gn];
                else if (col < 12) x = ycm[baseX + (col - 8) * NPOS + gn];
                m[j] = (__bf16)x;
            }
            *(bf4v*)(LD + MST + pp * 128 + ((8 * fg) ^ ((pp & 7) << 4))) = m;
        }
    }
    // hx halo rows 0 and 129 (clamped)
    if (tid < 32) {
        const int side = tid & 1;
        const int fg = tid >> 1;
        const int row = side ? 129 : 0;
        const int gn = side ? min(n0 + 128, NPOS - 1) : max(n0 - 1, 0);
        bf4v h;
        #pragma unroll
        for (int j = 0; j < 4; ++j) h[j] = (__bf16)hx[baseH + (4 * fg + j) * NPOS + gn];
        *(bf4v*)(LD + HXT + row * 128 + ((8 * fg) ^ ((row & 7) << 4))) = h;
    }
    __syncthreads();

    const int lane = tid & 63, wid = tid >> 6;
    const int s = lane >> 4, q = lane & 15;

    auto ldA = [&](int frag) -> bf8v {
        return *(const bf8v*)(ws + ((size_t)frag << 10) + ((size_t)lane << 4));
    };
    auto ldBias = [&](int frag) -> f4 {
        return *(const f4*)(ws + ((size_t)frag << 10) + ((size_t)lane << 4));
    };
    auto ldB = [&](int base, int row, int h) -> bf8v {   // feats h*32+8s .. +7 at position-row
        return *(const bf8v*)(LD + base + row * 128 + ((((h << 6) | (s << 4))) ^ ((row & 7) << 4)));
    };
    auto stAct = [&](int row, int t, f4 v, bool relu) {  // C-frag (t, regs 0-3) -> act tile
        bf4v h;
        #pragma unroll
        for (int r = 0; r < 4; ++r) {
            float x = v[r]; if (relu) x = fmaxf(x, 0.f);
            h[r] = (__bf16)x;
        }
        *(bf4v*)(LD + ACT + row * 128 + (((t << 5) | (s << 3)) ^ ((row & 7) << 4))) = h;
    };

    #pragma unroll 1
    for (int c = 0; c < 2; ++c) {
        const int p = wid * 32 + c * 16 + q;     // block-rel position 0..127
        const int gn = n0 + p;

        // ======== pc / fc / yc MLPs, summed after layer-2 ReLU ========
        f4 sum3[4];
        #pragma unroll
        for (int m = 0; m < 3; ++m) {
            bf8v b0, b1;
            if (m == 0)      { b0 = ldB(HXT, p,     0); b1 = ldB(HXT, p,     1); }  // hx[n-1]
            else if (m == 1) { b0 = ldB(HXT, p + 2, 0); b1 = ldB(HXT, p + 2, 1); }  // hx[n+1]
            else             { b0 = ldB(HYT, p,     0); b1 = ldB(HYT, p,     1); }  // hy
            bf8v b2 = ldB(HXT, p + 1, 0), b3 = ldB(HXT, p + 1, 1);                  // hx[n]
            bf8v b4 = ldB(MST, p, 0);                                               // messages
            const int w1 = m * 20, bb = 158 + m * 8;
            #pragma unroll
            for (int t = 0; t < 4; ++t) {
                f4 a = ldBias(bb + t);
                a = MF(ldA(w1 + t),      b0, a);
                a = MF(ldA(w1 + 4 + t),  b1, a);
                a = MF(ldA(w1 + 8 + t),  b2, a);
                a = MF(ldA(w1 + 12 + t), b3, a);
                a = MF(ldA(w1 + 16 + t), b4, a);
                stAct(p, t, a, true);
            }
            bf8v c0 = ldB(ACT, p, 0), c1 = ldB(ACT, p, 1);
            const int w2 = 60 + m * 8;
            #pragma unroll
            for (int t = 0; t < 4; ++t) {
                f4 a = ldBias(bb + 4 + t);
                a = MF(ldA(w2 + t),     c0, a);
                a = MF(ldA(w2 + 4 + t), c1, a);
                #pragma unroll
                for (int r = 0; r < 4; ++r) {
                    float x = fmaxf(a[r], 0.f);
                    if (m == 0) sum3[t][r] = x; else sum3[t][r] += x;
                }
            }
        }

        // ======== nd MLP -> U ========
        #pragma unroll
        for (int t = 0; t < 4; ++t) stAct(p, t, sum3[t], false);
        {
            bf8v u0 = ldB(ACT, p, 0), u1 = ldB(ACT, p, 1);
            #pragma unroll
            for (int t = 0; t < 4; ++t) {
                f4 a = ldBias(182 + t);
                a = MF(ldA(84 + t), u0, a);
                a = MF(ldA(88 + t), u1, a);
                stAct(p, t, a, true);
            }
        }
        {
            bf8v u0 = ldB(ACT, p, 0), u1 = ldB(ACT, p, 1);
            #pragma unroll
            for (int t = 0; t < 4; ++t) {
                f4 a = ldBias(186 + t);
                a = MF(ldA(92 + t), u0, a);
                a = MF(ldA(96 + t), u1, a);
                stAct(p, t, a, true);                       // act = U
            }
        }

        // ======== GRU ========
        {
            bf8v u0 = ldB(ACT, p, 0), u1 = ldB(ACT, p, 1);          // U
            bf8v h0 = ldB(HXT, p + 1, 0), h1 = ldB(HXT, p + 1, 1);  // hprev
            f4 rz[8], ig[4], hg[4];
            #pragma unroll
            for (int t = 0; t < 8; ++t) {
                f4 a = ldBias(190 + t);
                a = MF(ldA(100 + t), u0, a);   // Wih kb0
                a = MF(ldA(112 + t), u1, a);   // Wih kb1
                a = MF(ldA(124 + t), h0, a);   // Whh kb0
                a = MF(ldA(136 + t), h1, a);   // Whh kb1
                rz[t] = a;
            }
            #pragma unroll
            for (int t = 0; t < 4; ++t) {
                f4 a = ldBias(198 + t);
                a = MF(ldA(108 + t), u0, a);
                a = MF(ldA(120 + t), u1, a);
                ig[t] = a;
                f4 g2 = ldBias(202 + t);
                g2 = MF(ldA(132 + t), h0, g2);
                g2 = MF(ldA(144 + t), h1, g2);
                hg[t] = g2;
            }
            float* outH = out + NB * 4 * NPOS + baseH;
            #pragma unroll
            for (int t = 0; t < 4; ++t) {
                const int hrow = p + 1;
                bf4v hh = *(const bf4v*)(LD + HXT + hrow * 128 +
                                         (((t << 5) | (s << 3)) ^ ((hrow & 7) << 4)));
                bf4v hnb;
                #pragma unroll
                for (int r = 0; r < 4; ++r) {
                    float rr = sigm(rz[t][r]);
                    float zz = sigm(rz[t + 4][r]);
                    float nn = tanh_f(ig[t][r] + rr * hg[t][r]);
                    float hp = (float)hh[r];
                    float hn = nn + zz * (hp - nn);
                    outH[(16 * t + 4 * s + r) * NPOS + gn] = hn;
                    hnb[r] = (__bf16)hn;
                }
                *(bf4v*)(LD + ACT + p * 128 + (((t << 5) | (s << 3)) ^ ((p & 7) << 4))) = hnb;
            }
        }

        // ======== decoder ========
        {
            bf8v d0 = ldB(ACT, p, 0), d1 = ldB(ACT, p, 1);          // hnew
            #pragma unroll
            for (int t = 0; t < 4; ++t) {
                f4 a = ldBias(206 + t);
                a = MF(ldA(148 + t), d0, a);
                a = MF(ldA(152 + t), d1, a);
                stAct(p, t, a, true);
            }
            bf8v e0 = ldB(ACT, p, 0), e1 = ldB(ACT, p, 1);
            f4 ep = ldBias(210);
            ep = MF(ldA(156), e0, ep);
            ep = MF(ldA(157), e1, ep);
            if (s == 0) {
                #pragma unroll
                for (int r = 0; r < 4; ++r) out[baseX + r * NPOS + gn] = ep[r];
            }
        }
    }
}

extern "C" void kernel_launch(void* const* d_in, const int* in_sizes, int n_in,
                              void* d_out, int out_size, void* d_ws, size_t ws_size,
                              hipStream_t stream) {
    const float* hx   = (const float*)d_in[0];
    const float* pcm  = (const float*)d_in[1];
    const float* fcm  = (const float*)d_in[2];
    const float* ycm  = (const float*)d_in[3];
    const float* hy   = (const float*)d_in[4];

    prep_kernel<<<dim3(NFRAG), dim3(64), 0, stream>>>(
        (const float*)d_in[5],  (const float*)d_in[6],  (const float*)d_in[7],  (const float*)d_in[8],
        (const float*)d_in[9],  (const float*)d_in[10], (const float*)d_in[11], (const float*)d_in[12],
        (const float*)d_in[13], (const float*)d_in[14], (const float*)d_in[15], (const float*)d_in[16],
        (const float*)d_in[17], (const float*)d_in[18], (const float*)d_in[19], (const float*)d_in[20],
        (const float*)d_in[21], (const float*)d_in[22], (const float*)d_in[23], (const float*)d_in[24],
        (const float*)d_in[25], (const float*)d_in[26], (const float*)d_in[27], (const float*)d_in[28],
        (char*)d_ws);

    kgnn_main<<<dim3(NB * 32), dim3(256), 0, stream>>>(
        hx, pcm, fcm, ycm, hy, (const char*)d_ws, (float*)d_out);
}

// Round 4
// 140.525 us; speedup vs baseline: 16.6041x; 5.6111x over previous
//
#include <hip/hip_runtime.h>

#define NPOS 4096
#define NB   64

typedef __bf16 bf8v __attribute__((ext_vector_type(8)));
typedef __bf16 bf4v __attribute__((ext_vector_type(4)));
typedef float  f4   __attribute__((ext_vector_type(4)));

__device__ __forceinline__ float sigm(float x)   { return 1.0f / (1.0f + __expf(-x)); }
__device__ __forceinline__ float tanh_f(float x) { return 1.0f - 2.0f / (1.0f + __expf(2.0f * x)); }

__device__ __forceinline__ f4 MF(bf8v a, bf8v b, f4 c) {
    return __builtin_amdgcn_mfma_f32_16x16x32_bf16(a, b, c, 0, 0, 0);
}

// ---------------- frag index map (1KB frags in d_ws) ----------------
// 0-19   W1pc [kb*4+t]   20-39 W1fc   40-59 W1yc        (kb=0..4, t=0..3)
// 60-67  W2pc [kb*4+t]   68-75 W2fc   76-83 W2yc        (kb=0..1)
// 84-91  ndW1            92-99 ndW2
// 100-123 Wih [kb*12+t]  124-147 Whh                    (t=0..11)
// 148-155 decW1          156-157 decW2 [kb]
// biases (f32 frags): 158 pcb1(4) 162 pcb2 166 fcb1 170 fcb2 174 ycb1 178 ycb2
// 182 ndb1 186 ndb2 190 bR(4) 194 bZ(4) 198 bIG(4) 202 bHG(4) 206 db1(4) 210 db2(1)
#define NFRAG 211

__global__ __launch_bounds__(64) void prep_kernel(
    const float* __restrict__ pcW1, const float* __restrict__ pcb1, const float* __restrict__ pcW2, const float* __restrict__ pcb2,
    const float* __restrict__ fcW1, const float* __restrict__ fcb1, const float* __restrict__ fcW2, const float* __restrict__ fcb2,
    const float* __restrict__ ycW1, const float* __restrict__ ycb1, const float* __restrict__ ycW2, const float* __restrict__ ycb2,
    const float* __restrict__ ndW1, const float* __restrict__ ndb1, const float* __restrict__ ndW2, const float* __restrict__ ndb2,
    const float* __restrict__ Wih,  const float* __restrict__ bih,  const float* __restrict__ Whh,  const float* __restrict__ bhh,
    const float* __restrict__ dW1,  const float* __restrict__ db1,  const float* __restrict__ dW2,  const float* __restrict__ db2,
    char* __restrict__ ws)
{
    const int f = blockIdx.x, l = threadIdx.x;
    const int sg = l >> 4, c16 = l & 15;
    char* dst = ws + (size_t)f * 1024 + (size_t)l * 16;

    if (f < 158) {
        const float* W = nullptr; int t = 0, kb = 0, ncol = 64, mlp = -1, kind = 0;
        if (f < 60)       { mlp = f / 20; int r = f % 20; kb = r >> 2; t = r & 3;
                            W = (mlp == 0 ? pcW1 : (mlp == 1 ? fcW1 : ycW1)); kind = 1; }
        else if (f < 84)  { int g = f - 60; int w = g >> 3; int r = g & 7; kb = r >> 2; t = r & 3;
                            W = (w == 0 ? pcW2 : (w == 1 ? fcW2 : ycW2)); }
        else if (f < 92)  { int r = f - 84; kb = r >> 2; t = r & 3; W = ndW1; }
        else if (f < 100) { int r = f - 92; kb = r >> 2; t = r & 3; W = ndW2; }
        else if (f < 124) { int r = f - 100; kb = r / 12; t = r % 12; W = Wih; ncol = 192; }
        else if (f < 148) { int r = f - 124; kb = r / 12; t = r % 12; W = Whh; ncol = 192; }
        else if (f < 156) { int r = f - 148; kb = r >> 2; t = r & 3; W = dW1; }
        else              { kb = f - 156; t = 0; W = dW2; kind = 2; }
        const int row = 16 * t + c16;
        bf8v v;
        #pragma unroll
        for (int j = 0; j < 8; ++j) {
            int k = kb * 32 + sg * 8 + j;
            float x;
            if (kind == 1 && kb == 4) {            // W1 message block: mlp owns cols mlp*4..+3
                int kk = k - 128 - mlp * 4;
                x = (kk >= 0 && kk < 4) ? W[(128 + kk) * 64 + row] : 0.f;
            } else if (kind == 2) {                // decW2 [64][4], rows 4..15 zero
                x = (row < 4) ? W[k * 4 + row] : 0.f;
            } else {
                x = W[k * ncol + row];
            }
            v[j] = (__bf16)x;
        }
        *(bf8v*)dst = v;
    } else {
        const int g = f - 158;
        f4 o;
        #pragma unroll
        for (int r = 0; r < 4; ++r) {
            float x = 0.f; int t;
            if (g < 32) {
                t = g & 3; int fi = 16 * t + 4 * sg + r;
                switch (g >> 2) {
                    case 0: x = pcb1[fi]; break; case 1: x = pcb2[fi]; break;
                    case 2: x = fcb1[fi]; break; case 3: x = fcb2[fi]; break;
                    case 4: x = ycb1[fi]; break; case 5: x = ycb2[fi]; break;
                    case 6: x = ndb1[fi]; break; default: x = ndb2[fi]; break;
                }
            } else if (g < 40) { t = g - 32; int fi = 16 * t + 4 * sg + r; x = bih[fi] + bhh[fi]; }
            else if (g < 44)   { t = g - 40; x = bih[128 + 16 * t + 4 * sg + r]; }
            else if (g < 48)   { t = g - 44; x = bhh[128 + 16 * t + 4 * sg + r]; }
            else if (g < 52)   { t = g - 48; x = db1[16 * t + 4 * sg + r]; }
            else               { x = (sg == 0) ? db2[r] : 0.f; }
            o[r] = x;
        }
        *(f4*)dst = o;
    }
}

// ---------------- LDS layout (bytes) ----------------
#define HXT 0              // 130 rows x 128B (pos n0-1 .. n0+128), swizzled
#define HYT 16640          // 128 rows x 128B
#define MST 33024          // 128 rows x  80B pitch (32 bf16 cols, 12 real)
#define ACT 43264          // 128 rows x 128B
#define LDSZ 59648

__global__ __launch_bounds__(256, 2) void kgnn_main(
    const float* __restrict__ hx,  const float* __restrict__ pcm,
    const float* __restrict__ fcm, const float* __restrict__ ycm,
    const float* __restrict__ hy,
    const char*  __restrict__ ws,  float* __restrict__ out)
{
    __shared__ __align__(16) char LD[LDSZ];
    const int tid  = threadIdx.x;
    const int b    = blockIdx.x >> 5;
    const int tile = blockIdx.x & 31;
    const int n0   = tile * 128;
    const int baseH = b * 64 * NPOS;
    const int baseX = b * 4 * NPOS;

    // ---------------- staging ----------------
    #pragma unroll
    for (int it = 0; it < 8; ++it) {
        const int idx = it * 256 + tid;
        const int pp = idx & 127, fg = idx >> 7;          // fg 0..15
        const int gn = n0 + pp;
        {
            bf4v h;
            #pragma unroll
            for (int j = 0; j < 4; ++j) h[j] = (__bf16)hx[baseH + (4 * fg + j) * NPOS + gn];
            const int row = pp + 1;
            *(bf4v*)(LD + HXT + row * 128 + ((8 * fg) ^ ((row & 7) << 4))) = h;
        }
        {
            bf4v h;
            #pragma unroll
            for (int j = 0; j < 4; ++j) h[j] = (__bf16)hy[baseH + (4 * fg + j) * NPOS + gn];
            *(bf4v*)(LD + HYT + pp * 128 + ((8 * fg) ^ ((pp & 7) << 4))) = h;
        }
    }
    // messages: 32 cols (0-3 pcm, 4-7 fcm, 8-11 ycm, rest zero), 80B pitch, no swizzle
    #pragma unroll
    for (int it = 0; it < 4; ++it) {
        const int idx = it * 256 + tid;
        const int pp = idx & 127, fgc = idx >> 7;         // fgc 0..7
        const int gn = n0 + pp;
        bf4v m;
        #pragma unroll
        for (int j = 0; j < 4; ++j) {
            const int col = 4 * fgc + j;
            float x = 0.f;
            if      (col < 4)  x = pcm[baseX + col * NPOS + gn];
            else if (col < 8)  x = fcm[baseX + (col - 4) * NPOS + gn];
            else if (col < 12) x = ycm[baseX + (col - 8) * NPOS + gn];
            m[j] = (__bf16)x;
        }
        *(bf4v*)(LD + MST + pp * 80 + 8 * fgc) = m;
    }
    // hx halo rows 0 and 129 (clamped)
    if (tid < 32) {
        const int side = tid & 1;
        const int fg = tid >> 1;
        const int row = side ? 129 : 0;
        const int gn = side ? min(n0 + 128, NPOS - 1) : max(n0 - 1, 0);
        bf4v h;
        #pragma unroll
        for (int j = 0; j < 4; ++j) h[j] = (__bf16)hx[baseH + (4 * fg + j) * NPOS + gn];
        *(bf4v*)(LD + HXT + row * 128 + ((8 * fg) ^ ((row & 7) << 4))) = h;
    }
    __syncthreads();

    const int lane = tid & 63, wid = tid >> 6;
    const int s = lane >> 4, q = lane & 15;
    const int Pv[2] = { wid * 32 + q, wid * 32 + 16 + q };

    auto ldA = [&](int frag) -> bf8v {
        return *(const bf8v*)(ws + ((size_t)frag << 10) + ((size_t)lane << 4));
    };
    auto ldBias = [&](int frag) -> f4 {
        return *(const f4*)(ws + ((size_t)frag << 10) + ((size_t)lane << 4));
    };
    auto ldB = [&](int base, int row, int h) -> bf8v {
        return *(const bf8v*)(LD + base + row * 128 + ((((h << 6) | (s << 4))) ^ ((row & 7) << 4)));
    };
    auto ldBmsg = [&](int row) -> bf8v {
        return *(const bf8v*)(LD + MST + row * 80 + 16 * s);
    };
    auto stAct = [&](int row, int t, f4 v, bool relu) {
        bf4v h;
        #pragma unroll
        for (int r = 0; r < 4; ++r) {
            float x = v[r]; if (relu) x = fmaxf(x, 0.f);
            h[r] = (__bf16)x;
        }
        *(bf4v*)(LD + ACT + row * 128 + (((t << 5) | (s << 3)) ^ ((row & 7) << 4))) = h;
    };

    // ======== pc / fc / yc MLPs (c-fused: both 16-position groups per A-load) ========
    bf8v hxn0[2], hxn1[2], msgB[2];
    #pragma unroll
    for (int cc = 0; cc < 2; ++cc) {
        hxn0[cc] = ldB(HXT, Pv[cc] + 1, 0);
        hxn1[cc] = ldB(HXT, Pv[cc] + 1, 1);
        msgB[cc] = ldBmsg(Pv[cc]);
    }
    f4 sum3[2][4];
    #pragma unroll
    for (int m = 0; m < 3; ++m) {
        bf8v e0[2], e1[2];
        #pragma unroll
        for (int cc = 0; cc < 2; ++cc) {
            if (m == 0)      { e0[cc] = ldB(HXT, Pv[cc],     0); e1[cc] = ldB(HXT, Pv[cc],     1); }
            else if (m == 1) { e0[cc] = ldB(HXT, Pv[cc] + 2, 0); e1[cc] = ldB(HXT, Pv[cc] + 2, 1); }
            else             { e0[cc] = ldB(HYT, Pv[cc],     0); e1[cc] = ldB(HYT, Pv[cc],     1); }
        }
        const int w1 = m * 20, bb = 158 + m * 8;
        f4 a[2][4];
        #pragma unroll
        for (int t = 0; t < 4; ++t) { f4 bv = ldBias(bb + t); a[0][t] = bv; a[1][t] = bv; }
        #pragma unroll
        for (int t = 0; t < 4; ++t) { bf8v A = ldA(w1 + t);      a[0][t] = MF(A, e0[0],   a[0][t]); a[1][t] = MF(A, e0[1],   a[1][t]); }
        #pragma unroll
        for (int t = 0; t < 4; ++t) { bf8v A = ldA(w1 + 4 + t);  a[0][t] = MF(A, e1[0],   a[0][t]); a[1][t] = MF(A, e1[1],   a[1][t]); }
        #pragma unroll
        for (int t = 0; t < 4; ++t) { bf8v A = ldA(w1 + 8 + t);  a[0][t] = MF(A, hxn0[0], a[0][t]); a[1][t] = MF(A, hxn0[1], a[1][t]); }
        #pragma unroll
        for (int t = 0; t < 4; ++t) { bf8v A = ldA(w1 + 12 + t); a[0][t] = MF(A, hxn1[0], a[0][t]); a[1][t] = MF(A, hxn1[1], a[1][t]); }
        #pragma unroll
        for (int t = 0; t < 4; ++t) { bf8v A = ldA(w1 + 16 + t); a[0][t] = MF(A, msgB[0], a[0][t]); a[1][t] = MF(A, msgB[1], a[1][t]); }
        #pragma unroll
        for (int cc = 0; cc < 2; ++cc)
            #pragma unroll
            for (int t = 0; t < 4; ++t) stAct(Pv[cc], t, a[cc][t], true);

        bf8v c0[2] = { ldB(ACT, Pv[0], 0), ldB(ACT, Pv[1], 0) };
        bf8v c1[2] = { ldB(ACT, Pv[0], 1), ldB(ACT, Pv[1], 1) };
        const int w2 = 60 + m * 8;
        f4 a2[2][4];
        #pragma unroll
        for (int t = 0; t < 4; ++t) { f4 bv = ldBias(bb + 4 + t); a2[0][t] = bv; a2[1][t] = bv; }
        #pragma unroll
        for (int t = 0; t < 4; ++t) { bf8v A = ldA(w2 + t);     a2[0][t] = MF(A, c0[0], a2[0][t]); a2[1][t] = MF(A, c0[1], a2[1][t]); }
        #pragma unroll
        for (int t = 0; t < 4; ++t) { bf8v A = ldA(w2 + 4 + t); a2[0][t] = MF(A, c1[0], a2[0][t]); a2[1][t] = MF(A, c1[1], a2[1][t]); }
        #pragma unroll
        for (int cc = 0; cc < 2; ++cc)
            #pragma unroll
            for (int t = 0; t < 4; ++t)
                #pragma unroll
                for (int r = 0; r < 4; ++r) {
                    float x = fmaxf(a2[cc][t][r], 0.f);
                    if (m == 0) sum3[cc][t][r] = x; else sum3[cc][t][r] += x;
                }
    }

    // ======== nd MLP -> U (ends in ACT) ========
    #pragma unroll
    for (int cc = 0; cc < 2; ++cc)
        #pragma unroll
        for (int t = 0; t < 4; ++t) stAct(Pv[cc], t, sum3[cc][t], false);
    #pragma unroll
    for (int L = 0; L < 2; ++L) {
        bf8v u0[2] = { ldB(ACT, Pv[0], 0), ldB(ACT, Pv[1], 0) };
        bf8v u1[2] = { ldB(ACT, Pv[0], 1), ldB(ACT, Pv[1], 1) };
        const int wb = (L == 0) ? 84 : 92, bi = (L == 0) ? 182 : 186;
        f4 a[2][4];
        #pragma unroll
        for (int t = 0; t < 4; ++t) { f4 bv = ldBias(bi + t); a[0][t] = bv; a[1][t] = bv; }
        #pragma unroll
        for (int t = 0; t < 4; ++t) { bf8v A = ldA(wb + t);     a[0][t] = MF(A, u0[0], a[0][t]); a[1][t] = MF(A, u0[1], a[1][t]); }
        #pragma unroll
        for (int t = 0; t < 4; ++t) { bf8v A = ldA(wb + 4 + t); a[0][t] = MF(A, u1[0], a[0][t]); a[1][t] = MF(A, u1[1], a[1][t]); }
        #pragma unroll
        for (int cc = 0; cc < 2; ++cc)
            #pragma unroll
            for (int t = 0; t < 4; ++t) stAct(Pv[cc], t, a[cc][t], true);
    }

    // ======== GRU (sequential passes: hg -> r -> r*hg -> ig -> n -> z -> hnew) ========
    {
        bf8v uu0[2] = { ldB(ACT, Pv[0], 0), ldB(ACT, Pv[1], 0) };
        bf8v uu1[2] = { ldB(ACT, Pv[0], 1), ldB(ACT, Pv[1], 1) };
        bf8v hh0[2] = { ldB(HXT, Pv[0] + 1, 0), ldB(HXT, Pv[1] + 1, 0) };
        bf8v hh1[2] = { ldB(HXT, Pv[0] + 1, 1), ldB(HXT, Pv[1] + 1, 1) };

        f4 g[2][4];
        #pragma unroll
        for (int t = 0; t < 4; ++t) { f4 bv = ldBias(202 + t); g[0][t] = bv; g[1][t] = bv; }
        #pragma unroll
        for (int t = 0; t < 4; ++t) { bf8v A = ldA(132 + t); g[0][t] = MF(A, hh0[0], g[0][t]); g[1][t] = MF(A, hh0[1], g[1][t]); }
        #pragma unroll
        for (int t = 0; t < 4; ++t) { bf8v A = ldA(144 + t); g[0][t] = MF(A, hh1[0], g[0][t]); g[1][t] = MF(A, hh1[1], g[1][t]); }

        {
            f4 rr[2][4];
            #pragma unroll
            for (int t = 0; t < 4; ++t) { f4 bv = ldBias(190 + t); rr[0][t] = bv; rr[1][t] = bv; }
            #pragma unroll
            for (int t = 0; t < 4; ++t) { bf8v A = ldA(100 + t); rr[0][t] = MF(A, uu0[0], rr[0][t]); rr[1][t] = MF(A, uu0[1], rr[1][t]); }
            #pragma unroll
            for (int t = 0; t < 4; ++t) { bf8v A = ldA(112 + t); rr[0][t] = MF(A, uu1[0], rr[0][t]); rr[1][t] = MF(A, uu1[1], rr[1][t]); }
            #pragma unroll
            for (int t = 0; t < 4; ++t) { bf8v A = ldA(124 + t); rr[0][t] = MF(A, hh0[0], rr[0][t]); rr[1][t] = MF(A, hh0[1], rr[1][t]); }
            #pragma unroll
            for (int t = 0; t < 4; ++t) { bf8v A = ldA(136 + t); rr[0][t] = MF(A, hh1[0], rr[0][t]); rr[1][t] = MF(A, hh1[1], rr[1][t]); }
            #pragma unroll
            for (int cc = 0; cc < 2; ++cc)
                #pragma unroll
                for (int t = 0; t < 4; ++t)
                    #pragma unroll
                    for (int r = 0; r < 4; ++r) g[cc][t][r] = sigm(rr[cc][t][r]) * g[cc][t][r];
        }
        {
            f4 gi[2][4];
            #pragma unroll
            for (int t = 0; t < 4; ++t) { f4 bv = ldBias(198 + t); gi[0][t] = bv; gi[1][t] = bv; }
            #pragma unroll
            for (int t = 0; t < 4; ++t) { bf8v A = ldA(108 + t); gi[0][t] = MF(A, uu0[0], gi[0][t]); gi[1][t] = MF(A, uu0[1], gi[1][t]); }
            #pragma unroll
            for (int t = 0; t < 4; ++t) { bf8v A = ldA(120 + t); gi[0][t] = MF(A, uu1[0], gi[0][t]); gi[1][t] = MF(A, uu1[1], gi[1][t]); }
            #pragma unroll
            for (int cc = 0; cc < 2; ++cc)
                #pragma unroll
                for (int t = 0; t < 4; ++t)
                    #pragma unroll
                    for (int r = 0; r < 4; ++r) g[cc][t][r] = tanh_f(gi[cc][t][r] + g[cc][t][r]);   // n-gate
        }
        f4 zz[2][4];
        #pragma unroll
        for (int t = 0; t < 4; ++t) { f4 bv = ldBias(194 + t); zz[0][t] = bv; zz[1][t] = bv; }
        #pragma unroll
        for (int t = 0; t < 4; ++t) { bf8v A = ldA(104 + t); zz[0][t] = MF(A, uu0[0], zz[0][t]); zz[1][t] = MF(A, uu0[1], zz[1][t]); }
        #pragma unroll
        for (int t = 0; t < 4; ++t) { bf8v A = ldA(116 + t); zz[0][t] = MF(A, uu1[0], zz[0][t]); zz[1][t] = MF(A, uu1[1], zz[1][t]); }
        #pragma unroll
        for (int t = 0; t < 4; ++t) { bf8v A = ldA(128 + t); zz[0][t] = MF(A, hh0[0], zz[0][t]); zz[1][t] = MF(A, hh0[1], zz[1][t]); }
        #pragma unroll
        for (int t = 0; t < 4; ++t) { bf8v A = ldA(140 + t); zz[0][t] = MF(A, hh1[0], zz[0][t]); zz[1][t] = MF(A, hh1[1], zz[1][t]); }

        float* __restrict__ outH = out + NB * 4 * NPOS + baseH;
        #pragma unroll
        for (int cc = 0; cc < 2; ++cc) {
            const int hrow = Pv[cc] + 1;
            const int gn = n0 + Pv[cc];
            #pragma unroll
            for (int t = 0; t < 4; ++t) {
                bf4v hp4 = *(const bf4v*)(LD + HXT + hrow * 128 +
                                          (((t << 5) | (s << 3)) ^ ((hrow & 7) << 4)));
                bf4v hnb;
                #pragma unroll
                for (int r = 0; r < 4; ++r) {
                    float z  = sigm(zz[cc][t][r]);
                    float nn = g[cc][t][r];
                    float hp = (float)hp4[r];
                    float hn = nn + z * (hp - nn);
                    outH[(16 * t + 4 * s + r) * NPOS + gn] = hn;
                    hnb[r] = (__bf16)hn;
                }
                *(bf4v*)(LD + ACT + Pv[cc] * 128 + (((t << 5) | (s << 3)) ^ ((Pv[cc] & 7) << 4))) = hnb;
            }
        }
    }

    // ======== decoder ========
    {
        bf8v d0[2] = { ldB(ACT, Pv[0], 0), ldB(ACT, Pv[1], 0) };
        bf8v d1[2] = { ldB(ACT, Pv[0], 1), ldB(ACT, Pv[1], 1) };
        f4 a[2][4];
        #pragma unroll
        for (int t = 0; t < 4; ++t) { f4 bv = ldBias(206 + t); a[0][t] = bv; a[1][t] = bv; }
        #pragma unroll
        for (int t = 0; t < 4; ++t) { bf8v A = ldA(148 + t); a[0][t] = MF(A, d0[0], a[0][t]); a[1][t] = MF(A, d0[1], a[1][t]); }
        #pragma unroll
        for (int t = 0; t < 4; ++t) { bf8v A = ldA(152 + t); a[0][t] = MF(A, d1[0], a[0][t]); a[1][t] = MF(A, d1[1], a[1][t]); }
        #pragma unroll
        for (int cc = 0; cc < 2; ++cc)
            #pragma unroll
            for (int t = 0; t < 4; ++t) stAct(Pv[cc], t, a[cc][t], true);

        bf8v e0[2] = { ldB(ACT, Pv[0], 0), ldB(ACT, Pv[1], 0) };
        bf8v e1[2] = { ldB(ACT, Pv[0], 1), ldB(ACT, Pv[1], 1) };
        f4 ep[2];
        { f4 bv = ldBias(210); ep[0] = bv; ep[1] = bv; }
        { bf8v A = ldA(156); ep[0] = MF(A, e0[0], ep[0]); ep[1] = MF(A, e0[1], ep[1]); }
        { bf8v A = ldA(157); ep[0] = MF(A, e1[0], ep[0]); ep[1] = MF(A, e1[1], ep[1]); }
        if (s == 0) {
            #pragma unroll
            for (int cc = 0; cc < 2; ++cc) {
                const int gn = n0 + Pv[cc];
                #pragma unroll
                for (int r = 0; r < 4; ++r) out[baseX + r * NPOS + gn] = ep[cc][r];
            }
        }
    }
}

extern "C" void kernel_launch(void* const* d_in, const int* in_sizes, int n_in,
                              void* d_out, int out_size, void* d_ws, size_t ws_size,
                              hipStream_t stream) {
    const float* hx   = (const float*)d_in[0];
    const float* pcm  = (const float*)d_in[1];
    const float* fcm  = (const float*)d_in[2];
    const float* ycm  = (const float*)d_in[3];
    const float* hy   = (const float*)d_in[4];

    prep_kernel<<<dim3(NFRAG), dim3(64), 0, stream>>>(
        (const float*)d_in[5],  (const float*)d_in[6],  (const float*)d_in[7],  (const float*)d_in[8],
        (const float*)d_in[9],  (const float*)d_in[10], (const float*)d_in[11], (const float*)d_in[12],
        (const float*)d_in[13], (const float*)d_in[14], (const float*)d_in[15], (const float*)d_in[16],
        (const float*)d_in[17], (const float*)d_in[18], (const float*)d_in[19], (const float*)d_in[20],
        (const float*)d_in[21], (const float*)d_in[22], (const float*)d_in[23], (const float*)d_in[24],
        (const float*)d_in[25], (const float*)d_in[26], (const float*)d_in[27], (const float*)d_in[28],
        (char*)d_ws);

    kgnn_main<<<dim3(NB * 32), dim3(256), 0, stream>>>(
        hx, pcm, fcm, ycm, hy, (const char*)d_ws, (float*)d_out);
}